// Round 7
// baseline (293.900 us; speedup 1.0000x reference)
//
#include <hip/hip_runtime.h>

#define B_SZ    16
#define T_LEN   1024
#define C_CH    32
#define TC      (T_LEN * C_CH)      // 32768
#define S_MAIN  128
#define NB_P    400
#define P_TOP   60
#define OUT_CH  (NB_P + P_TOP)      // 460

typedef float        v4f __attribute__((ext_vector_type(4)));
typedef int          v4i __attribute__((ext_vector_type(4)));
typedef unsigned int v4u __attribute__((ext_vector_type(4)));

__device__ __forceinline__ unsigned short f32_to_bf16_rne(float f) {
    unsigned int u = __float_as_uint(f);
    unsigned int r = u + 0x7fffu + ((u >> 16) & 1u);
    return (unsigned short)(r >> 16);
}

__device__ __forceinline__ float leaky(float v) {
    return (v > 0.f) ? v : 0.3f * v;
}

// ---------------------------------------------------------------------------
// Kernel 1: transpose+pack x [B, T*C] f32 -> xb [T*C] x 32 B blocks:
// block = 16 batches bf16; half bh holds batches 8bh..8bh+7, uint m of a
// half = batches (8bh+2m, 8bh+2m+1) as (lo,hi).
// ---------------------------------------------------------------------------
__global__ __launch_bounds__(256) void transpose_pack(const float* __restrict__ x,
                                                      unsigned int* __restrict__ xb) {
    const int i = blockIdx.x * 256 + threadIdx.x;    // [0, TC)
    unsigned int u[8];
    #pragma unroll
    for (int k = 0; k < 8; ++k) {
        float v0 = x[(size_t)(2 * k)     * TC + i];
        float v1 = x[(size_t)(2 * k + 1) * TC + i];
        u[k] = (unsigned int)f32_to_bf16_rne(v0) |
               ((unsigned int)f32_to_bf16_rne(v1) << 16);
    }
    v4u a = { u[0], u[1], u[2], u[3] };
    v4u b = { u[4], u[5], u[6], u[7] };
    v4u* out = (v4u*)xb;
    out[(size_t)i * 2]     = a;   // batches 0..7
    out[(size_t)i * 2 + 1] = b;   // batches 8..15
}

// ---------------------------------------------------------------------------
// Patch compute v7: bf16 gathers, nontemporal (no L1 line allocation ->
// sector-granular L2 traffic: 32 B/index instead of 64 B line).
// One wave per pair. lane = j*2+bh: j in [0,32) owns 4 indices, bh = batch
// half (16 B = 8 bf16 batches). Per pair: 256 x 16 B requests = 4 KB.
// Normal (write-back) stores. nt on stream-once idx/W.
// ---------------------------------------------------------------------------
template <int NPAIR_P, int NROWS, bool TO_WS>
__global__ __launch_bounds__(256) void patch_nt(
    const v4u*   __restrict__ xb4,    // [TC*2] 16 B blocks
    const int*   __restrict__ idx,    // [NROWS*NPAIR_P, 128]
    const float* __restrict__ W,      // [NROWS*NPAIR_P, 128]
    const float* __restrict__ bias,   // [NROWS*NPAIR_P]
    float*       __restrict__ dst)    // ws [16,NROWS,NPAIR_P] or out [16,T,460]
{
    const int wave = threadIdx.x >> 6;
    const int lane = threadIdx.x & 63;
    const int pair = blockIdx.x * 4 + wave;
    const int j    = lane >> 1;       // 0..31: owns indices 4j..4j+3
    const int bh   = lane & 1;        // batch half

    const v4i iv = __builtin_nontemporal_load((const v4i*)(idx + (size_t)pair * 128) + j);
    const v4f wv = __builtin_nontemporal_load((const v4f*)(W   + (size_t)pair * 128) + j);

    float acc[8];
    #pragma unroll
    for (int k = 0; k < 8; ++k) acc[k] = 0.f;

    const int ixs[4] = { iv.x, iv.y, iv.z, iv.w };
    const float wts[4] = { wv.x, wv.y, wv.z, wv.w };
    #pragma unroll
    for (int m = 0; m < 4; ++m) {
        const v4u gv = __builtin_nontemporal_load(xb4 + (size_t)ixs[m] * 2 + bh);
        const float wt = wts[m];
        acc[0] += __uint_as_float(gv.x << 16)         * wt;
        acc[1] += __uint_as_float(gv.x & 0xffff0000u) * wt;
        acc[2] += __uint_as_float(gv.y << 16)         * wt;
        acc[3] += __uint_as_float(gv.y & 0xffff0000u) * wt;
        acc[4] += __uint_as_float(gv.z << 16)         * wt;
        acc[5] += __uint_as_float(gv.z & 0xffff0000u) * wt;
        acc[6] += __uint_as_float(gv.w << 16)         * wt;
        acc[7] += __uint_as_float(gv.w & 0xffff0000u) * wt;
    }

    // Reduce over j (preserve bh = bit 0): masks 2,4,8,16,32.
    #pragma unroll
    for (int m = 2; m <= 32; m <<= 1)
        #pragma unroll
        for (int k = 0; k < 8; ++k)
            acc[k] += __shfl_xor(acc[k], m);

    if (j == 0) {                     // lanes 0 (batches 0-7), 1 (batches 8-15)
        const float bv = bias[pair];
        const int row = pair / NPAIR_P;
        const int p   = pair - row * NPAIR_P;
        #pragma unroll
        for (int k = 0; k < 8; ++k) {
            const int b = bh * 8 + k;
            const float val = leaky(acc[k] + bv);
            if (TO_WS) {
                dst[((size_t)b * NROWS + row) * NPAIR_P + p] = val;
            } else {
                dst[((size_t)b * T_LEN + row) * OUT_CH + NB_P + p] = val;
            }
        }
    }
}

// ---------------------------------------------------------------------------
// Upsample main result x8 along time into the output (coalesced).
// out row = 460 floats = 115 float4; main part = first 100 float4.
// ---------------------------------------------------------------------------
__global__ __launch_bounds__(256) void upsample_main(const float* __restrict__ ws_main,
                                                     float* __restrict__ out) {
    const int o4 = blockIdx.x * 256 + threadIdx.x;   // < B*T*100 = 1,638,400
    const int row = o4 / 100;
    const int col = o4 - row * 100;
    const int b = row >> 10;         // /1024
    const int t = row & 1023;
    const int s = t >> 3;            // /STRETCH
    const v4f v = ((const v4f*)ws_main)[((size_t)b * S_MAIN + s) * 100 + col];
    ((v4f*)out)[(size_t)row * 115 + col] = v;
}

// ---------------------------------------------------------------------------
extern "C" void kernel_launch(void* const* d_in, const int* in_sizes, int n_in,
                              void* d_out, int out_size, void* d_ws, size_t ws_size,
                              hipStream_t stream) {
    const float* x      = (const float*)d_in[0];
    const float* W_main = (const float*)d_in[1];
    const float* b_main = (const float*)d_in[2];
    const float* W_top  = (const float*)d_in[3];
    const float* b_top  = (const float*)d_in[4];
    const int*  idx_main = (const int*)d_in[5];
    const int*  idx_top  = (const int*)d_in[6];
    float* out = (float*)d_out;

    unsigned int* xb   = (unsigned int*)d_ws;                         // 1 MB
    float* ws_main     = (float*)((char*)d_ws + (size_t)TC * 16 * 2); // 3.3 MB

    transpose_pack<<<TC / 256, 256, 0, stream>>>(x, xb);

    patch_nt<NB_P, S_MAIN, true>
        <<<(S_MAIN * NB_P) / 4, 256, 0, stream>>>((const v4u*)xb, idx_main, W_main, b_main, ws_main);

    patch_nt<P_TOP, T_LEN, false>
        <<<(T_LEN * P_TOP) / 4, 256, 0, stream>>>((const v4u*)xb, idx_top, W_top, b_top, out);

    upsample_main<<<(B_SZ * T_LEN * 100) / 256, 256, 0, stream>>>(ws_main, out);
}

// Round 8
// 240.520 us; speedup vs baseline: 1.2219x; 1.2219x over previous
//
#include <hip/hip_runtime.h>

#define B_SZ    16
#define T_LEN   1024
#define C_CH    32
#define TC      (T_LEN * C_CH)      // 32768
#define S_MAIN  128
#define NB_P    400
#define P_TOP   60
#define OUT_CH  (NB_P + P_TOP)      // 460

typedef float        v4f __attribute__((ext_vector_type(4)));
typedef int          v4i __attribute__((ext_vector_type(4)));
typedef unsigned int v4u __attribute__((ext_vector_type(4)));

__device__ __forceinline__ unsigned short f32_to_bf16_rne(float f) {
    unsigned int u = __float_as_uint(f);
    unsigned int r = u + 0x7fffu + ((u >> 16) & 1u);
    return (unsigned short)(r >> 16);
}

__device__ __forceinline__ float leaky(float v) {
    return (v > 0.f) ? v : 0.3f * v;
}

// ---------------------------------------------------------------------------
// Kernel 1: transpose+pack x [B, T*C] f32 -> xb: per index i a 32 B block =
// 16 batches bf16 (half bh = batches 8bh..8bh+7). Total 1 MB -> L2-resident.
// ---------------------------------------------------------------------------
__global__ __launch_bounds__(256) void transpose_pack(const float* __restrict__ x,
                                                      unsigned int* __restrict__ xb) {
    const int i = blockIdx.x * 256 + threadIdx.x;    // [0, TC)
    unsigned int u[8];
    #pragma unroll
    for (int k = 0; k < 8; ++k) {
        float v0 = x[(size_t)(2 * k)     * TC + i];
        float v1 = x[(size_t)(2 * k + 1) * TC + i];
        u[k] = (unsigned int)f32_to_bf16_rne(v0) |
               ((unsigned int)f32_to_bf16_rne(v1) << 16);
    }
    v4u a = { u[0], u[1], u[2], u[3] };
    v4u b = { u[4], u[5], u[6], u[7] };
    v4u* out = (v4u*)xb;
    out[(size_t)i * 2]     = a;   // batches 0..7
    out[(size_t)i * 2 + 1] = b;   // batches 8..15
}

// ---------------------------------------------------------------------------
// Patch compute v8: L2-resident-x gathers.
// One wave per pair. lane = j*2+bh: j in [0,32) owns 4 indices, bh = batch
// half (16 B). The two bh-lanes of an index hit the same 64 B line -> TA
// merges them: 128 line-requests/pair (minimum). Gathers are NORMAL loads
// (L2-allocate, xb stays hot); idx/W are NT (evict-first, can't displace xb).
// ---------------------------------------------------------------------------
template <int NPAIR_P, int NROWS, bool TO_WS>
__global__ __launch_bounds__(256) void patch_l2(
    const v4u*   __restrict__ xb4,    // [TC*2] 16 B half-blocks
    const int*   __restrict__ idx,    // [NROWS*NPAIR_P, 128]
    const float* __restrict__ W,      // [NROWS*NPAIR_P, 128]
    const float* __restrict__ bias,   // [NROWS*NPAIR_P]
    float*       __restrict__ dst)    // ws [16,NROWS,NPAIR_P] or out [16,T,460]
{
    const int wave = threadIdx.x >> 6;
    const int lane = threadIdx.x & 63;
    const int pair = blockIdx.x * 4 + wave;
    const int j    = lane >> 1;       // 0..31: owns indices 4j..4j+3
    const int bh   = lane & 1;        // batch half

    const v4i iv = __builtin_nontemporal_load((const v4i*)(idx + (size_t)pair * 128) + j);
    const v4f wv = __builtin_nontemporal_load((const v4f*)(W   + (size_t)pair * 128) + j);

    float acc[8];
    #pragma unroll
    for (int k = 0; k < 8; ++k) acc[k] = 0.f;

    const int   ixs[4] = { iv.x, iv.y, iv.z, iv.w };
    const float wts[4] = { wv.x, wv.y, wv.z, wv.w };
    #pragma unroll
    for (int m = 0; m < 4; ++m) {
        const v4u gv = xb4[(size_t)ixs[m] * 2 + bh];   // normal load: L2 keeps xb
        const float wt = wts[m];
        acc[0] += __uint_as_float(gv.x << 16)         * wt;
        acc[1] += __uint_as_float(gv.x & 0xffff0000u) * wt;
        acc[2] += __uint_as_float(gv.y << 16)         * wt;
        acc[3] += __uint_as_float(gv.y & 0xffff0000u) * wt;
        acc[4] += __uint_as_float(gv.z << 16)         * wt;
        acc[5] += __uint_as_float(gv.z & 0xffff0000u) * wt;
        acc[6] += __uint_as_float(gv.w << 16)         * wt;
        acc[7] += __uint_as_float(gv.w & 0xffff0000u) * wt;
    }

    // Reduce over j (preserve bh = bit 0): masks 2,4,8,16,32.
    #pragma unroll
    for (int m = 2; m <= 32; m <<= 1)
        #pragma unroll
        for (int k = 0; k < 8; ++k)
            acc[k] += __shfl_xor(acc[k], m);

    if (j == 0) {                     // lanes 0 (batches 0-7), 1 (batches 8-15)
        const float bv = bias[pair];
        const int row = pair / NPAIR_P;
        const int p   = pair - row * NPAIR_P;
        #pragma unroll
        for (int k = 0; k < 8; ++k) {
            const int b = bh * 8 + k;
            const float val = leaky(acc[k] + bv);
            if (TO_WS) {
                dst[((size_t)b * NROWS + row) * NPAIR_P + p] = val;
            } else {
                dst[((size_t)b * T_LEN + row) * OUT_CH + NB_P + p] = val;
            }
        }
    }
}

// ---------------------------------------------------------------------------
// Upsample main result x8 along time into the output (coalesced).
// out row = 460 floats = 115 float4; main part = first 100 float4.
// ---------------------------------------------------------------------------
__global__ __launch_bounds__(256) void upsample_main(const float* __restrict__ ws_main,
                                                     float* __restrict__ out) {
    const int o4 = blockIdx.x * 256 + threadIdx.x;   // < B*T*100 = 1,638,400
    const int row = o4 / 100;
    const int col = o4 - row * 100;
    const int b = row >> 10;         // /1024
    const int t = row & 1023;
    const int s = t >> 3;            // /STRETCH
    const v4f v = ((const v4f*)ws_main)[((size_t)b * S_MAIN + s) * 100 + col];
    ((v4f*)out)[(size_t)row * 115 + col] = v;
}

// ---------------------------------------------------------------------------
extern "C" void kernel_launch(void* const* d_in, const int* in_sizes, int n_in,
                              void* d_out, int out_size, void* d_ws, size_t ws_size,
                              hipStream_t stream) {
    const float* x      = (const float*)d_in[0];
    const float* W_main = (const float*)d_in[1];
    const float* b_main = (const float*)d_in[2];
    const float* W_top  = (const float*)d_in[3];
    const float* b_top  = (const float*)d_in[4];
    const int*  idx_main = (const int*)d_in[5];
    const int*  idx_top  = (const int*)d_in[6];
    float* out = (float*)d_out;

    unsigned int* xb   = (unsigned int*)d_ws;                         // 1 MB
    float* ws_main     = (float*)((char*)d_ws + (size_t)TC * 16 * 2); // 3.3 MB

    transpose_pack<<<TC / 256, 256, 0, stream>>>(x, xb);

    patch_l2<NB_P, S_MAIN, true>
        <<<(S_MAIN * NB_P) / 4, 256, 0, stream>>>((const v4u*)xb, idx_main, W_main, b_main, ws_main);

    patch_l2<P_TOP, T_LEN, false>
        <<<(T_LEN * P_TOP) / 4, 256, 0, stream>>>((const v4u*)xb, idx_top, W_top, b_top, out);

    upsample_main<<<(B_SZ * T_LEN * 100) / 256, 256, 0, stream>>>(ws_main, out);
}